// Round 1
// baseline (423.061 us; speedup 1.0000x reference)
//
#include <hip/hip_runtime.h>
#include <hip/hip_bf16.h>

// SubjectLayers: out[b,d] = sum_c x[b,c] * W[idx[b],c,d] + bias[idx[b],d]
// B=512, C=D=1024, 32 subjects, fp32.
// Strategy: group rows by subject (prep kernel), then one block per
// (row-chunk of <=16 rows, 256-wide d tile). W is streamed once per chunk;
// memory-bound floor ~128 MB of W reads.

#define N_SUBJ 32
#define B_ROWS 512
#define IN_CH_K 1024
#define OUT_CH_K 1024
#define ROWS_PER_CHUNK 16
#define MAX_CHUNKS 64          // worst case Sum ceil(n_s/16) <= 62
#define CTILE 256
#define DTILE 256

// d_ws layout (int32):
//   [0]                 n_chunks
//   [1 .. 1+3*64)       chunk entries {subject, start, cnt}
//   [256 .. 256+512)    perm (row indices sorted by subject)
#define ENT_OFF 1
#define PERM_OFF 256

__global__ __launch_bounds__(512) void build_groups(
    const int* __restrict__ idx, int* __restrict__ ws)
{
    __shared__ int counts[N_SUBJ];
    __shared__ int offs[N_SUBJ];
    __shared__ int cursor[N_SUBJ];
    const int t = threadIdx.x;
    if (t < N_SUBJ) counts[t] = 0;
    __syncthreads();
    const int s = idx[t] & (N_SUBJ - 1);
    atomicAdd(&counts[s], 1);
    __syncthreads();
    if (t == 0) {
        int acc = 0, nch = 0;
        for (int i = 0; i < N_SUBJ; ++i) {
            offs[i] = acc;
            cursor[i] = acc;
            acc += counts[i];
        }
        for (int i = 0; i < N_SUBJ; ++i) {
            for (int st = 0; st < counts[i]; st += ROWS_PER_CHUNK) {
                int c = counts[i] - st;
                if (c > ROWS_PER_CHUNK) c = ROWS_PER_CHUNK;
                ws[ENT_OFF + nch * 3 + 0] = i;
                ws[ENT_OFF + nch * 3 + 1] = offs[i] + st;
                ws[ENT_OFF + nch * 3 + 2] = c;
                ++nch;
            }
        }
        ws[0] = nch;
    }
    __syncthreads();
    const int pos = atomicAdd(&cursor[s], 1);
    ws[PERM_OFF + pos] = t;
}

__global__ __launch_bounds__(256) void subject_gemm(
    const float* __restrict__ x, const float* __restrict__ W,
    const float* __restrict__ bias, const int* __restrict__ ws,
    float* __restrict__ out)
{
    const int chunk = blockIdx.x;
    if (chunk >= ws[0]) return;
    const int s     = ws[ENT_OFF + chunk * 3 + 0];
    const int start = ws[ENT_OFF + chunk * 3 + 1];
    const int cnt   = ws[ENT_OFF + chunk * 3 + 2];
    const int dbase = blockIdx.y * DTILE;

    __shared__ float xs[ROWS_PER_CHUNK][CTILE];
    __shared__ int rowidx[ROWS_PER_CHUNK];

    const int t = threadIdx.x;
    if (t < ROWS_PER_CHUNK)
        rowidx[t] = (t < cnt) ? ws[PERM_OFF + start + t] : -1;
    __syncthreads();

    const int lane = t & 63;
    const int wave = t >> 6;           // 4 waves: wave w owns rows 4w..4w+3
    const int d    = dbase + lane * 4; // lane owns 4 consecutive d (float4)
    const int r0   = wave * 4;

    float4 acc0 = make_float4(0.f, 0.f, 0.f, 0.f);
    float4 acc1 = make_float4(0.f, 0.f, 0.f, 0.f);
    float4 acc2 = make_float4(0.f, 0.f, 0.f, 0.f);
    float4 acc3 = make_float4(0.f, 0.f, 0.f, 0.f);

    for (int c0 = 0; c0 < IN_CH_K; c0 += CTILE) {
        // stage x tile: row i, col t (coalesced 1KB per row); zero-fill
        // invalid rows so their FMAs are harmless.
        #pragma unroll
        for (int i = 0; i < ROWS_PER_CHUNK; ++i) {
            const int r = rowidx[i];
            xs[i][t] = (r >= 0) ? x[r * IN_CH_K + c0 + t] : 0.0f;
        }
        __syncthreads();

        const float* wp = W + ((size_t)s * IN_CH_K * OUT_CH_K)
                            + (size_t)c0 * OUT_CH_K + d;
        #pragma unroll 8
        for (int c = 0; c < CTILE; ++c) {
            const float4 w4 = *(const float4*)wp;
            wp += OUT_CH_K;
            const float xv0 = xs[r0 + 0][c];
            const float xv1 = xs[r0 + 1][c];
            const float xv2 = xs[r0 + 2][c];
            const float xv3 = xs[r0 + 3][c];
            acc0.x += xv0 * w4.x; acc0.y += xv0 * w4.y;
            acc0.z += xv0 * w4.z; acc0.w += xv0 * w4.w;
            acc1.x += xv1 * w4.x; acc1.y += xv1 * w4.y;
            acc1.z += xv1 * w4.z; acc1.w += xv1 * w4.w;
            acc2.x += xv2 * w4.x; acc2.y += xv2 * w4.y;
            acc2.z += xv2 * w4.z; acc2.w += xv2 * w4.w;
            acc3.x += xv3 * w4.x; acc3.y += xv3 * w4.y;
            acc3.z += xv3 * w4.z; acc3.w += xv3 * w4.w;
        }
        __syncthreads();
    }

    const float4 b4 = *(const float4*)&bias[s * OUT_CH_K + d];
    float4 accs[4] = {acc0, acc1, acc2, acc3};
    #pragma unroll
    for (int r = 0; r < 4; ++r) {
        const int rr = r0 + r;
        if (rr < cnt) {
            float4 o;
            o.x = accs[r].x + b4.x;
            o.y = accs[r].y + b4.y;
            o.z = accs[r].z + b4.z;
            o.w = accs[r].w + b4.w;
            *(float4*)&out[(size_t)rowidx[rr] * OUT_CH_K + d] = o;
        }
    }
}

extern "C" void kernel_launch(void* const* d_in, const int* in_sizes, int n_in,
                              void* d_out, int out_size, void* d_ws, size_t ws_size,
                              hipStream_t stream) {
    const float* x    = (const float*)d_in[0];
    const int*   idx  = (const int*)d_in[1];
    const float* W    = (const float*)d_in[2];
    const float* bias = (const float*)d_in[3];
    float* out = (float*)d_out;
    int* ws = (int*)d_ws;

    build_groups<<<1, 512, 0, stream>>>(idx, ws);

    dim3 grid(MAX_CHUNKS, OUT_CH_K / DTILE);  // (64, 4); extra chunks exit early
    subject_gemm<<<grid, 256, 0, stream>>>(x, W, bias, ws, out);
}

// Round 2
// 251.910 us; speedup vs baseline: 1.6794x; 1.6794x over previous
//
#include <hip/hip_runtime.h>
#include <hip/hip_bf16.h>

// SubjectLayers: out[b,d] = sum_c x[b,c] * W[idx[b],c,d] + bias[idx[b],d]
// B=512, C=D=1024, 32 subjects, fp32. Memory-bound on W (128 MB read once).
//
// R1 lesson: previous version was latency-bound (VALUBusy 4.7%, occupancy 8%,
// VGPR=40 -> no load batching). Fix: explicit 8-deep float4 load batches
// (ILP) + split C across blocks (TLP: ~992 blocks) with workspace partials
// and a reduce kernel (atomicAdd fallback if ws too small).

#define N_SUBJ 32
#define B_ROWS 512
#define IN_CH_K 1024
#define OUT_CH_K 1024
#define ROWS_PER_CHUNK 16
#define MAX_CHUNKS 64          // sum ceil(n_s/16) <= 62
#define CSEGS 4
#define CSEG 256               // IN_CH_K / CSEGS
#define DTILES 4
#define DTILE 256              // OUT_CH_K / DTILES

// d_ws layout:
//   int32 [0]                n_chunks
//   int32 [1 .. 1+3*64)      chunk entries {subject, start, cnt}
//   int32 [256 .. 768)       perm (row indices grouped by subject)
//   float [1024 ...)         partials: CSEGS x 512 x 1024 floats (8 MB)
#define ENT_OFF 1
#define PERM_OFF 256
#define PART_OFF_F 1024
#define PART_FLOATS (CSEGS * B_ROWS * OUT_CH_K)
#define WS_NEED_BYTES (4096 + (size_t)PART_FLOATS * 4)

__global__ __launch_bounds__(512) void build_groups(
    const int* __restrict__ idx, int* __restrict__ ws)
{
    __shared__ int counts[N_SUBJ];
    __shared__ int offs[N_SUBJ];
    __shared__ int cursor[N_SUBJ];
    const int t = threadIdx.x;
    if (t < N_SUBJ) counts[t] = 0;
    __syncthreads();
    const int s = idx[t] & (N_SUBJ - 1);
    atomicAdd(&counts[s], 1);
    __syncthreads();
    if (t == 0) {
        int acc = 0, nch = 0;
        for (int i = 0; i < N_SUBJ; ++i) {
            offs[i] = acc;
            cursor[i] = acc;
            acc += counts[i];
        }
        for (int i = 0; i < N_SUBJ; ++i) {
            for (int st = 0; st < counts[i]; st += ROWS_PER_CHUNK) {
                int c = counts[i] - st;
                if (c > ROWS_PER_CHUNK) c = ROWS_PER_CHUNK;
                ws[ENT_OFF + nch * 3 + 0] = i;
                ws[ENT_OFF + nch * 3 + 1] = offs[i] + st;
                ws[ENT_OFF + nch * 3 + 2] = c;
                ++nch;
            }
        }
        ws[0] = nch;
    }
    __syncthreads();
    const int pos = atomicAdd(&cursor[s], 1);
    ws[PERM_OFF + pos] = t;
}

// Atomic-path init: out[b,:] = bias[idx[b],:]
__global__ __launch_bounds__(256) void init_bias(
    const int* __restrict__ idx, const float* __restrict__ bias,
    float* __restrict__ out)
{
    const int b = blockIdx.x;
    const int s = idx[b];
    const int d = threadIdx.x * 4;
    *(float4*)&out[(size_t)b * OUT_CH_K + d] =
        *(const float4*)&bias[(size_t)s * OUT_CH_K + d];
}

// grid: (chunk, cseg, dtile); block 256 = 4 waves; wave w owns rows 4w..4w+3,
// lane owns 4 consecutive d. Inner loop: batches of 8 W-rows in registers.
template<bool ATOMIC>
__global__ __launch_bounds__(256) void subject_gemm(
    const float* __restrict__ x, const float* __restrict__ W,
    const int* __restrict__ ws, float* __restrict__ ws_part,
    float* __restrict__ out)
{
    const int chunk = blockIdx.x;
    if (chunk >= ws[0]) return;
    const int s     = ws[ENT_OFF + chunk * 3 + 0];
    const int start = ws[ENT_OFF + chunk * 3 + 1];
    const int cnt   = ws[ENT_OFF + chunk * 3 + 2];
    const int cbase = blockIdx.y * CSEG;
    const int dbase = blockIdx.z * DTILE;

    __shared__ float xs[ROWS_PER_CHUNK][CSEG];
    __shared__ int rowidx[ROWS_PER_CHUNK];

    const int t = threadIdx.x;
    if (t < ROWS_PER_CHUNK)
        rowidx[t] = (t < cnt) ? ws[PERM_OFF + start + t] : -1;
    __syncthreads();

    // stage x tile (16 rows x 256 c), zero-fill invalid rows
    #pragma unroll
    for (int i = 0; i < ROWS_PER_CHUNK; ++i) {
        const int r = rowidx[i];
        xs[i][t] = (r >= 0) ? x[(size_t)r * IN_CH_K + cbase + t] : 0.0f;
    }
    __syncthreads();

    const int lane = t & 63;
    const int wave = t >> 6;
    const int d    = dbase + lane * 4;
    const int r0   = wave * 4;

    float4 acc0 = make_float4(0.f, 0.f, 0.f, 0.f);
    float4 acc1 = make_float4(0.f, 0.f, 0.f, 0.f);
    float4 acc2 = make_float4(0.f, 0.f, 0.f, 0.f);
    float4 acc3 = make_float4(0.f, 0.f, 0.f, 0.f);

    const float* wbase = W + ((size_t)s * IN_CH_K * OUT_CH_K)
                           + (size_t)cbase * OUT_CH_K + d;

    for (int cb = 0; cb < CSEG; cb += 8) {
        float4 wbuf[8];
        #pragma unroll
        for (int j = 0; j < 8; ++j)
            wbuf[j] = *(const float4*)(wbase + (size_t)(cb + j) * OUT_CH_K);
        #pragma unroll
        for (int j = 0; j < 8; ++j) {
            const float xv0 = xs[r0 + 0][cb + j];
            const float xv1 = xs[r0 + 1][cb + j];
            const float xv2 = xs[r0 + 2][cb + j];
            const float xv3 = xs[r0 + 3][cb + j];
            const float4 w4 = wbuf[j];
            acc0.x += xv0 * w4.x; acc0.y += xv0 * w4.y;
            acc0.z += xv0 * w4.z; acc0.w += xv0 * w4.w;
            acc1.x += xv1 * w4.x; acc1.y += xv1 * w4.y;
            acc1.z += xv1 * w4.z; acc1.w += xv1 * w4.w;
            acc2.x += xv2 * w4.x; acc2.y += xv2 * w4.y;
            acc2.z += xv2 * w4.z; acc2.w += xv2 * w4.w;
            acc3.x += xv3 * w4.x; acc3.y += xv3 * w4.y;
            acc3.z += xv3 * w4.z; acc3.w += xv3 * w4.w;
        }
    }

    float4 accs[4] = {acc0, acc1, acc2, acc3};
    #pragma unroll
    for (int r = 0; r < 4; ++r) {
        const int rr = r0 + r;
        if (rr < cnt) {
            const size_t row = (size_t)rowidx[rr];
            if (ATOMIC) {
                float* o = &out[row * OUT_CH_K + d];
                atomicAdd(o + 0, accs[r].x);
                atomicAdd(o + 1, accs[r].y);
                atomicAdd(o + 2, accs[r].z);
                atomicAdd(o + 3, accs[r].w);
            } else {
                *(float4*)&ws_part[((size_t)blockIdx.y * B_ROWS + row)
                                   * OUT_CH_K + d] = accs[r];
            }
        }
    }
}

// out[b,d] = bias[idx[b],d] + sum_k part[k][b][d]
__global__ __launch_bounds__(256) void reduce_parts(
    const int* __restrict__ idx, const float* __restrict__ bias,
    const float* __restrict__ part, float* __restrict__ out)
{
    const int b = blockIdx.x;
    const int s = idx[b];
    const int d = threadIdx.x * 4;
    float4 a = *(const float4*)&bias[(size_t)s * OUT_CH_K + d];
    #pragma unroll
    for (int k = 0; k < CSEGS; ++k) {
        const float4 p = *(const float4*)
            &part[((size_t)k * B_ROWS + b) * OUT_CH_K + d];
        a.x += p.x; a.y += p.y; a.z += p.z; a.w += p.w;
    }
    *(float4*)&out[(size_t)b * OUT_CH_K + d] = a;
}

extern "C" void kernel_launch(void* const* d_in, const int* in_sizes, int n_in,
                              void* d_out, int out_size, void* d_ws, size_t ws_size,
                              hipStream_t stream) {
    const float* x    = (const float*)d_in[0];
    const int*   idx  = (const int*)d_in[1];
    const float* W    = (const float*)d_in[2];
    const float* bias = (const float*)d_in[3];
    float* out = (float*)d_out;
    int* ws = (int*)d_ws;
    float* ws_part = (float*)ws + PART_OFF_F;

    build_groups<<<1, 512, 0, stream>>>(idx, ws);

    dim3 grid(MAX_CHUNKS, CSEGS, DTILES);  // (64,4,4) -> ~992 active blocks
    if (ws_size >= WS_NEED_BYTES) {
        subject_gemm<false><<<grid, 256, 0, stream>>>(x, W, ws, ws_part, out);
        reduce_parts<<<B_ROWS, 256, 0, stream>>>(idx, bias, ws_part, out);
    } else {
        init_bias<<<B_ROWS, 256, 0, stream>>>(idx, bias, out);
        subject_gemm<true><<<grid, 256, 0, stream>>>(x, W, ws, ws_part, out);
    }
}